// Round 1
// baseline (645.498 us; speedup 1.0000x reference)
//
#include <hip/hip_runtime.h>

// ---------------------------------------------------------------------------
// FusionCrossAttention: out = softmax((x Wq^T)(kv Wk^T)^T / sqrt(hd)) (kv Wv^T) Wo^T
// B=4, T_q=1024, T_kv=4096, D=1024, H=16, hd=64
// All intermediates bf16 (stored as ushort bits), accumulation f32 via MFMA.
// ---------------------------------------------------------------------------

typedef __attribute__((ext_vector_type(4))) float f32x4;
typedef __attribute__((ext_vector_type(8))) short bf16x8;

__device__ __forceinline__ unsigned short f2bf(float f) {
  unsigned u = __float_as_uint(f);
  u = (u + 0x7fffu + ((u >> 16) & 1u)) >> 16;   // round-to-nearest-even
  return (unsigned short)u;
}

#define GLD_LDS16(g, l)                                                     \
  __builtin_amdgcn_global_load_lds(                                        \
      (const __attribute__((address_space(1))) unsigned int*)(const void*)(g), \
      (__attribute__((address_space(3))) unsigned int*)(void*)(l), 16, 0, 0)

// ---------------------------------------------------------------------------
// f32 -> bf16 conversion (vectorized, grid-stride). n % 4 == 0.
// ---------------------------------------------------------------------------
__global__ void cvt_f32_bf16(const float* __restrict__ in,
                             unsigned short* __restrict__ out, int n) {
  int stride = gridDim.x * blockDim.x * 4;
  for (int i = (blockIdx.x * blockDim.x + threadIdx.x) * 4; i < n; i += stride) {
    float4 v = *(const float4*)(in + i);
    ushort4 o;
    o.x = f2bf(v.x); o.y = f2bf(v.y); o.z = f2bf(v.z); o.w = f2bf(v.w);
    *(ushort4*)(out + i) = o;
  }
}

// ---------------------------------------------------------------------------
// 128x128x(K) GEMM, C[i][j] = sum_k A[i][k] * Bt[j][k]   (B^T input layout)
// m97 structure: BK=32, 4 waves (2x2), each wave 4x4 frags of 16x16x32 bf16.
// global_load_lds width-16 staging with pre-swizzled global source granules
// (granule g_src = g ^ ((row>>1)&3)) so LDS fragment reads are ~conflict-free.
// Requires M%128==0, N%128==0, K%32==0, grid = (M/128)*(N/128) % 8 == 0.
// ---------------------------------------------------------------------------
template <int WRITE_BF16>
__global__ __launch_bounds__(256) void gemm_bt(
    const unsigned short* __restrict__ A, const unsigned short* __restrict__ Bt,
    void* __restrict__ Cp, int M, int N, int K, int ldc) {
  __shared__ __align__(16) unsigned short Ash[4096];  // [128][32]
  __shared__ __align__(16) unsigned short Bsh[4096];  // [128][32]

  int tiles_n = N >> 7;
  int nwg = gridDim.x;
  int wg = blockIdx.x;
  int cpx = nwg >> 3;                       // bijective: nwg % 8 == 0 guaranteed
  wg = (wg & 7) * cpx + (wg >> 3);          // XCD-aware swizzle
  int tm = wg / tiles_n, tn = wg - tm * tiles_n;

  int tid = threadIdx.x;
  int lane = tid & 63, wave = tid >> 6;
  int wr = wave >> 1, wc = wave & 1;
  int brow = tm << 7, bcol = tn << 7;

  int fr = lane & 15, fg = lane >> 4;
  int swz = (fr >> 1) & 3;                  // read-side XOR mask

  // staging: wave handles chunks 2w,2w+1 of A and of B (16 rows x 32 cols each)
  int srow = lane >> 2;                     // 0..15 row within chunk
  int sg = (lane & 3) ^ ((srow >> 1) & 3);  // pre-swizzled source granule

  const unsigned short* aG0 = A + (size_t)(brow + wave * 32 + srow) * K + sg * 8;
  const unsigned short* aG1 = A + (size_t)(brow + wave * 32 + 16 + srow) * K + sg * 8;
  const unsigned short* bG0 = Bt + (size_t)(bcol + wave * 32 + srow) * K + sg * 8;
  const unsigned short* bG1 = Bt + (size_t)(bcol + wave * 32 + 16 + srow) * K + sg * 8;
  unsigned short* aL0 = Ash + wave * 1024;
  unsigned short* aL1 = Ash + wave * 1024 + 512;
  unsigned short* bL0 = Bsh + wave * 1024;
  unsigned short* bL1 = Bsh + wave * 1024 + 512;

  const f32x4 zero4 = {0.f, 0.f, 0.f, 0.f};
  f32x4 acc[4][4];
#pragma unroll
  for (int m = 0; m < 4; ++m)
#pragma unroll
    for (int n = 0; n < 4; ++n) acc[m][n] = zero4;

  for (int k0 = 0; k0 < K; k0 += 32) {
    GLD_LDS16(aG0 + k0, aL0);
    GLD_LDS16(aG1 + k0, aL1);
    GLD_LDS16(bG0 + k0, bL0);
    GLD_LDS16(bG1 + k0, bL1);
    __syncthreads();  // drains vmcnt before LDS reads

    bf16x8 af[4], bfr[4];
#pragma unroll
    for (int m = 0; m < 4; ++m) {
      int r = wr * 64 + m * 16 + fr;
      af[m] = *(const bf16x8*)(Ash + r * 32 + ((fg ^ swz) * 8));
    }
#pragma unroll
    for (int n = 0; n < 4; ++n) {
      int r = wc * 64 + n * 16 + fr;
      bfr[n] = *(const bf16x8*)(Bsh + r * 32 + ((fg ^ swz) * 8));
    }
#pragma unroll
    for (int m = 0; m < 4; ++m)
#pragma unroll
      for (int n = 0; n < 4; ++n)
        acc[m][n] =
            __builtin_amdgcn_mfma_f32_16x16x32_bf16(af[m], bfr[n], acc[m][n], 0, 0, 0);
    __syncthreads();  // all waves done reading before next stage overwrites
  }

  // epilogue: C/D layout (verified): row = (lane>>4)*4 + j, col = lane&15
  int crow = brow + wr * 64 + fg * 4;
  int ccol = bcol + wc * 64 + fr;
#pragma unroll
  for (int m = 0; m < 4; ++m)
#pragma unroll
    for (int n = 0; n < 4; ++n)
#pragma unroll
      for (int j = 0; j < 4; ++j) {
        size_t off = (size_t)(crow + m * 16 + j) * ldc + (ccol + n * 16);
        if (WRITE_BF16)
          ((unsigned short*)Cp)[off] = f2bf(acc[m][n][j]);
        else
          ((float*)Cp)[off] = acc[m][n][j];
      }
}

// ---------------------------------------------------------------------------
// Flash attention. Grid: 1024 blocks = (b:4, h:16, qtile:16). Block: 4 waves,
// each wave owns 16 q-rows. KV chunk = 32. K staged [32][64] (XOR swz r&7),
// V staged from the TRANSPOSED projection vt (1024 x 16384) as [64][32]
// (XOR swz (d>>1)&3) so the PV B-operand is a contiguous 16B LDS read.
// P goes through a per-wave padded LDS tile (stride 40 ushorts = 80B, 16B-aligned).
// ---------------------------------------------------------------------------
__global__ __launch_bounds__(256) void attn_fwd(
    const unsigned short* __restrict__ qp,  // (4096, 1024)
    const unsigned short* __restrict__ kp,  // (16384, 1024)
    const unsigned short* __restrict__ vt,  // (1024, 16384) = V^T per (b,h)
    unsigned short* __restrict__ ao) {      // (4096, 1024)
  __shared__ __align__(16) unsigned short Ksh[2048];    // [32][64]
  __shared__ __align__(16) unsigned short Vsh[2048];    // [64][32]
  __shared__ __align__(16) unsigned short Psh[4][640];  // per-wave [16][40]

  int idx = blockIdx.x;
  int qt = idx & 15;
  int h = (idx >> 4) & 15;
  int b = idx >> 8;
  int tid = threadIdx.x;
  int lane = tid & 63, w = tid >> 6;
  int fr = lane & 15, fg = lane >> 4;

  const float SC = 0.125f * 1.44269504088896f;  // 1/sqrt(64) * log2(e)

  // Q fragments held in registers (A-operand layout)
  int qrow = b * 1024 + qt * 64 + w * 16 + fr;
  bf16x8 qf0 = *(const bf16x8*)(qp + (size_t)qrow * 1024 + h * 64 + fg * 8);
  bf16x8 qf1 = *(const bf16x8*)(qp + (size_t)qrow * 1024 + h * 64 + 32 + fg * 8);

  const f32x4 zero4 = {0.f, 0.f, 0.f, 0.f};
  f32x4 o[4];
#pragma unroll
  for (int n = 0; n < 4; ++n) o[n] = zero4;
  float m[4], ssum[4];
#pragma unroll
  for (int j = 0; j < 4; ++j) { m[j] = -1e30f; ssum[j] = 0.f; }

  // K staging: wave w covers rows w*8 .. w*8+7 (8 rows x 8 granules)
  int rK = w * 8 + (lane >> 3);
  int gK = (lane & 7) ^ ((lane >> 3) & 7);
  const unsigned short* ksrc = kp + (size_t)(b * 4096 + rK) * 1024 + h * 64 + gK * 8;
  // V staging: wave w covers d rows w*16 .. w*16+15 (16 rows x 4 granules)
  int dV = w * 16 + (lane >> 2);
  int gV = (lane & 3) ^ ((lane >> 3) & 3);
  const unsigned short* vsrc = vt + (size_t)(h * 64 + dV) * 16384 + b * 4096 + gV * 8;

  unsigned short* pw = &Psh[w][0];

  for (int kv0 = 0; kv0 < 4096; kv0 += 32) {
    GLD_LDS16(ksrc + (size_t)kv0 * 1024, Ksh + w * 512);
    GLD_LDS16(vsrc + kv0, Vsh + w * 512);
    __syncthreads();

    // ---- S = Q K^T for 32 kv cols (2 sub-tiles of 16) ----
    f32x4 S0 = zero4, S1 = zero4;
#pragma unroll
    for (int kk = 0; kk < 2; ++kk) {
      int r0 = fr;        // sub 0 rows 0..15
      int r1 = 16 + fr;   // sub 1 rows 16..31
      int g = fg + kk * 4;
      bf16x8 kf0 = *(const bf16x8*)(Ksh + r0 * 64 + ((g ^ (r0 & 7)) * 8));
      bf16x8 kf1 = *(const bf16x8*)(Ksh + r1 * 64 + ((g ^ (r1 & 7)) * 8));
      bf16x8 qv = kk ? qf1 : qf0;
      S0 = __builtin_amdgcn_mfma_f32_16x16x32_bf16(qv, kf0, S0, 0, 0, 0);
      S1 = __builtin_amdgcn_mfma_f32_16x16x32_bf16(qv, kf1, S1, 0, 0, 0);
    }

    // ---- online softmax (rows = (lane>>4)*4+j, cols = lane&15 (+16)) ----
    float s0[4], s1[4], cm[4];
#pragma unroll
    for (int j = 0; j < 4; ++j) {
      s0[j] = S0[j] * SC;
      s1[j] = S1[j] * SC;
      cm[j] = fmaxf(s0[j], s1[j]);
    }
#pragma unroll
    for (int mask = 1; mask <= 8; mask <<= 1)
#pragma unroll
      for (int j = 0; j < 4; ++j) cm[j] = fmaxf(cm[j], __shfl_xor(cm[j], mask));

    float fsc[4];
#pragma unroll
    for (int j = 0; j < 4; ++j) {
      float mn = fmaxf(m[j], cm[j]);
      fsc[j] = exp2f(m[j] - mn);
      m[j] = mn;
    }
    float p0[4], p1[4], rs[4];
#pragma unroll
    for (int j = 0; j < 4; ++j) {
      p0[j] = exp2f(s0[j] - m[j]);
      p1[j] = exp2f(s1[j] - m[j]);
      rs[j] = p0[j] + p1[j];
    }
#pragma unroll
    for (int mask = 1; mask <= 8; mask <<= 1)
#pragma unroll
      for (int j = 0; j < 4; ++j) rs[j] += __shfl_xor(rs[j], mask);
#pragma unroll
    for (int j = 0; j < 4; ++j) ssum[j] = ssum[j] * fsc[j] + rs[j];
#pragma unroll
    for (int n = 0; n < 4; ++n)
#pragma unroll
      for (int j = 0; j < 4; ++j) o[n][j] *= fsc[j];

    // ---- P -> per-wave LDS (C-layout scatter), read back in A-layout ----
#pragma unroll
    for (int j = 0; j < 4; ++j) {
      int pr = fg * 4 + j;
      pw[pr * 40 + fr] = f2bf(p0[j]);
      pw[pr * 40 + 16 + fr] = f2bf(p1[j]);
    }
    bf16x8 pa = *(const bf16x8*)(pw + fr * 40 + fg * 8);

    // ---- O += P V ----
#pragma unroll
    for (int n = 0; n < 4; ++n) {
      int d = n * 16 + fr;
      bf16x8 vf = *(const bf16x8*)(Vsh + d * 32 + ((fg ^ ((d >> 1) & 3)) * 8));
      o[n] = __builtin_amdgcn_mfma_f32_16x16x32_bf16(pa, vf, o[n], 0, 0, 0);
    }
    __syncthreads();  // protect Ksh/Vsh before next stage
  }

  // ---- normalize + store bf16 ----
#pragma unroll
  for (int j = 0; j < 4; ++j) {
    float inv = 1.0f / ssum[j];
    int row = b * 1024 + qt * 64 + w * 16 + fg * 4 + j;
#pragma unroll
    for (int n = 0; n < 4; ++n)
      ao[(size_t)row * 1024 + h * 64 + n * 16 + fr] = f2bf(o[n][j] * inv);
  }
}

// ---------------------------------------------------------------------------
// Launcher. Inputs: query(4M f32), kv_source(16M f32), w_q,w_k,w_v,w_o (1M f32).
// Workspace layout (128 MiB):
//   [0,8)    q_bf     [8,40)  kv_bf    [40,48) weights bf16 x4
//   [48,56)  qproj    [56,88) kproj    [88,120) v^T proj   [120,128) attn out
// ---------------------------------------------------------------------------
extern "C" void kernel_launch(void* const* d_in, const int* in_sizes, int n_in,
                              void* d_out, int out_size, void* d_ws, size_t ws_size,
                              hipStream_t stream) {
  const float* query = (const float*)d_in[0];
  const float* kvs = (const float*)d_in[1];
  const float* wq = (const float*)d_in[2];
  const float* wk = (const float*)d_in[3];
  const float* wv = (const float*)d_in[4];
  const float* wo = (const float*)d_in[5];
  float* out = (float*)d_out;
  char* ws = (char*)d_ws;
  const size_t MB = 1ull << 20;

  unsigned short* q_bf = (unsigned short*)(ws + 0 * MB);
  unsigned short* kv_bf = (unsigned short*)(ws + 8 * MB);
  unsigned short* wq_bf = (unsigned short*)(ws + 40 * MB);
  unsigned short* wk_bf = (unsigned short*)(ws + 42 * MB);
  unsigned short* wv_bf = (unsigned short*)(ws + 44 * MB);
  unsigned short* wo_bf = (unsigned short*)(ws + 46 * MB);
  unsigned short* qp = (unsigned short*)(ws + 48 * MB);
  unsigned short* kp = (unsigned short*)(ws + 56 * MB);
  unsigned short* vt = (unsigned short*)(ws + 88 * MB);
  unsigned short* ao = (unsigned short*)(ws + 120 * MB);

  cvt_f32_bf16<<<1024, 256, 0, stream>>>(query, q_bf, 4096 * 1024);
  cvt_f32_bf16<<<2048, 256, 0, stream>>>(kvs, kv_bf, 16384 * 1024);
  cvt_f32_bf16<<<256, 256, 0, stream>>>(wq, wq_bf, 1024 * 1024);
  cvt_f32_bf16<<<256, 256, 0, stream>>>(wk, wk_bf, 1024 * 1024);
  cvt_f32_bf16<<<256, 256, 0, stream>>>(wv, wv_bf, 1024 * 1024);
  cvt_f32_bf16<<<256, 256, 0, stream>>>(wo, wo_bf, 1024 * 1024);

  // q = query @ Wq^T            (4096 x 1024)
  gemm_bt<1><<<256, 256, 0, stream>>>(q_bf, wq_bf, qp, 4096, 1024, 1024, 1024);
  // k = kv @ Wk^T               (16384 x 1024)
  gemm_bt<1><<<1024, 256, 0, stream>>>(kv_bf, wk_bf, kp, 16384, 1024, 1024, 1024);
  // v^T = Wv @ kv^T             (1024 x 16384)  -- same kernel, swapped operands
  gemm_bt<1><<<1024, 256, 0, stream>>>(wv_bf, kv_bf, vt, 1024, 16384, 1024, 16384);

  attn_fwd<<<1024, 256, 0, stream>>>(qp, kp, vt, ao);

  // out = attn_out @ Wo^T       (4096 x 1024) f32
  gemm_bt<0><<<256, 256, 0, stream>>>(ao, wo_bf, out, 4096, 1024, 1024, 1024);
}

// Round 2
// 528.963 us; speedup vs baseline: 1.2203x; 1.2203x over previous
//
#include <hip/hip_runtime.h>

// ---------------------------------------------------------------------------
// FusionCrossAttention: out = softmax((x Wq^T)(kv Wk^T)^T / sqrt(hd)) (kv Wv^T) Wo^T
// B=4, T_q=1024, T_kv=4096, D=1024, H=16, hd=64
// All intermediates bf16 (stored as ushort bits), accumulation f32 via MFMA.
// ---------------------------------------------------------------------------

typedef __attribute__((ext_vector_type(4))) float f32x4;
typedef __attribute__((ext_vector_type(8))) short bf16x8;

__device__ __forceinline__ unsigned short f2bf(float f) {
  unsigned u = __float_as_uint(f);
  u = (u + 0x7fffu + ((u >> 16) & 1u)) >> 16;   // round-to-nearest-even
  return (unsigned short)u;
}

#define GLD_LDS16(g, l)                                                     \
  __builtin_amdgcn_global_load_lds(                                        \
      (const __attribute__((address_space(1))) unsigned int*)(const void*)(g), \
      (__attribute__((address_space(3))) unsigned int*)(void*)(l), 16, 0, 0)

// ---------------------------------------------------------------------------
// f32 -> bf16 conversion (vectorized, grid-stride). n % 4 == 0.
// ---------------------------------------------------------------------------
__global__ void cvt_f32_bf16(const float* __restrict__ in,
                             unsigned short* __restrict__ out, int n) {
  int stride = gridDim.x * blockDim.x * 4;
  for (int i = (blockIdx.x * blockDim.x + threadIdx.x) * 4; i < n; i += stride) {
    float4 v = *(const float4*)(in + i);
    ushort4 o;
    o.x = f2bf(v.x); o.y = f2bf(v.y); o.z = f2bf(v.z); o.w = f2bf(v.w);
    *(ushort4*)(out + i) = o;
  }
}

// ---------------------------------------------------------------------------
// 128x128x(K) GEMM, C[i][j] = sum_k A[i][k] * Bt[j][k]   (B^T input layout)
// m97 structure: BK=32, 4 waves (2x2), each wave 4x4 frags of 16x16x32 bf16.
// Requires M%128==0, N%128==0, K%32==0, grid = (M/128)*(N/128) % 8 == 0.
// ---------------------------------------------------------------------------
template <int WRITE_BF16>
__global__ __launch_bounds__(256) void gemm_bt(
    const unsigned short* __restrict__ A, const unsigned short* __restrict__ Bt,
    void* __restrict__ Cp, int M, int N, int K, int ldc) {
  __shared__ __align__(16) unsigned short Ash[4096];  // [128][32]
  __shared__ __align__(16) unsigned short Bsh[4096];  // [128][32]

  int tiles_n = N >> 7;
  int nwg = gridDim.x;
  int wg = blockIdx.x;
  int cpx = nwg >> 3;                       // bijective: nwg % 8 == 0 guaranteed
  wg = (wg & 7) * cpx + (wg >> 3);          // XCD-aware swizzle
  int tm = wg / tiles_n, tn = wg - tm * tiles_n;

  int tid = threadIdx.x;
  int lane = tid & 63, wave = tid >> 6;
  int wr = wave >> 1, wc = wave & 1;
  int brow = tm << 7, bcol = tn << 7;

  int fr = lane & 15, fg = lane >> 4;
  int swz = (fr >> 1) & 3;                  // read-side XOR mask

  int srow = lane >> 2;                     // 0..15 row within chunk
  int sg = (lane & 3) ^ ((srow >> 1) & 3);  // pre-swizzled source granule

  const unsigned short* aG0 = A + (size_t)(brow + wave * 32 + srow) * K + sg * 8;
  const unsigned short* aG1 = A + (size_t)(brow + wave * 32 + 16 + srow) * K + sg * 8;
  const unsigned short* bG0 = Bt + (size_t)(bcol + wave * 32 + srow) * K + sg * 8;
  const unsigned short* bG1 = Bt + (size_t)(bcol + wave * 32 + 16 + srow) * K + sg * 8;
  unsigned short* aL0 = Ash + wave * 1024;
  unsigned short* aL1 = Ash + wave * 1024 + 512;
  unsigned short* bL0 = Bsh + wave * 1024;
  unsigned short* bL1 = Bsh + wave * 1024 + 512;

  const f32x4 zero4 = {0.f, 0.f, 0.f, 0.f};
  f32x4 acc[4][4];
#pragma unroll
  for (int m = 0; m < 4; ++m)
#pragma unroll
    for (int n = 0; n < 4; ++n) acc[m][n] = zero4;

  for (int k0 = 0; k0 < K; k0 += 32) {
    GLD_LDS16(aG0 + k0, aL0);
    GLD_LDS16(aG1 + k0, aL1);
    GLD_LDS16(bG0 + k0, bL0);
    GLD_LDS16(bG1 + k0, bL1);
    __syncthreads();  // drains vmcnt before LDS reads

    bf16x8 af[4], bfr[4];
#pragma unroll
    for (int m = 0; m < 4; ++m) {
      int r = wr * 64 + m * 16 + fr;
      af[m] = *(const bf16x8*)(Ash + r * 32 + ((fg ^ swz) * 8));
    }
#pragma unroll
    for (int n = 0; n < 4; ++n) {
      int r = wc * 64 + n * 16 + fr;
      bfr[n] = *(const bf16x8*)(Bsh + r * 32 + ((fg ^ swz) * 8));
    }
#pragma unroll
    for (int m = 0; m < 4; ++m)
#pragma unroll
      for (int n = 0; n < 4; ++n)
        acc[m][n] =
            __builtin_amdgcn_mfma_f32_16x16x32_bf16(af[m], bfr[n], acc[m][n], 0, 0, 0);
    __syncthreads();  // all waves done reading before next stage overwrites
  }

  int crow = brow + wr * 64 + fg * 4;
  int ccol = bcol + wc * 64 + fr;
#pragma unroll
  for (int m = 0; m < 4; ++m)
#pragma unroll
    for (int n = 0; n < 4; ++n)
#pragma unroll
      for (int j = 0; j < 4; ++j) {
        size_t off = (size_t)(crow + m * 16 + j) * ldc + (ccol + n * 16);
        if (WRITE_BF16)
          ((unsigned short*)Cp)[off] = f2bf(acc[m][n][j]);
        else
          ((float*)Cp)[off] = acc[m][n][j];
      }
}

// ---------------------------------------------------------------------------
// Flash attention, KVBLK=128. Grid: 1024 blocks = (b:4, h:16, qtile:16),
// XCD-swizzled so all 16 q-tiles of one (b,h) land on the same XCD (K/V L2
// reuse). Block: 4 waves, each wave owns 16 q-rows, full 128-col KV chunk.
// Per iteration: 8 gld_lds per wave, 1 barrier, 16 QK^T MFMA + softmax +
// 16 PV MFMA, 1 barrier.  K staged [128][64] (granule swz g^(r&7)); V staged
// from transposed projection vt as [64][128] (swz g^(d&15)); P via per-wave
// padded LDS [16][136] (272B rows, 16B aligned).
// ---------------------------------------------------------------------------
__global__ __launch_bounds__(256) void attn_fwd(
    const unsigned short* __restrict__ qp,  // (4096, 1024)
    const unsigned short* __restrict__ kp,  // (16384, 1024)
    const unsigned short* __restrict__ vt,  // (1024, 16384) = V^T per (b,h)
    unsigned short* __restrict__ ao) {      // (4096, 1024)
  __shared__ __align__(16) unsigned short Ksh[128 * 64];   // 16 KB
  __shared__ __align__(16) unsigned short Vsh[64 * 128];   // 16 KB
  __shared__ __align__(16) unsigned short Psh[4][16 * 136];  // 17 KB

  // XCD swizzle: launch-index n runs on XCD n%8; give each XCD 128
  // consecutive logical blocks = 8 whole (b,h) groups (16 q-tiles each).
  int idx = (blockIdx.x & 7) * 128 + (blockIdx.x >> 3);
  int qt = idx & 15;
  int h = (idx >> 4) & 15;
  int b = idx >> 8;
  int tid = threadIdx.x;
  int lane = tid & 63, w = tid >> 6;
  int fr = lane & 15, fg = lane >> 4;

  const float SC = 0.125f * 1.44269504088896f;  // 1/sqrt(64) * log2(e)

  // Q fragments held in registers (A-operand layout)
  int qrow = b * 1024 + qt * 64 + w * 16 + fr;
  bf16x8 qf0 = *(const bf16x8*)(qp + (size_t)qrow * 1024 + h * 64 + fg * 8);
  bf16x8 qf1 = *(const bf16x8*)(qp + (size_t)qrow * 1024 + h * 64 + 32 + fg * 8);

  const f32x4 zero4 = {0.f, 0.f, 0.f, 0.f};
  f32x4 o[4];
#pragma unroll
  for (int n = 0; n < 4; ++n) o[n] = zero4;
  float m[4], ssum[4];
#pragma unroll
  for (int j = 0; j < 4; ++j) { m[j] = -1e30f; ssum[j] = 0.f; }

  // K staging: wave w stages rows w*32..w*32+31; call i covers 8 rows x 8
  // granules; lane l -> row i*8+(l>>3), src granule (l&7)^((l>>3)&7).
  int rK = w * 32 + (lane >> 3);
  int gK = (lane & 7) ^ ((lane >> 3) & 7);
  const unsigned short* ksrc = kp + (size_t)(b * 4096 + rK) * 1024 + h * 64 + gK * 8;
  // V staging: wave w stages d-rows w*16..w*16+15; call i covers 4 rows x 16
  // granules; lane l -> row i*4+(l>>4), src granule (l&15)^((i*4+(l>>4))&15).
  const unsigned short* vsrc[4];
#pragma unroll
  for (int i = 0; i < 4; ++i) {
    int dV = w * 16 + i * 4 + (lane >> 4);
    int gV = (lane & 15) ^ ((i * 4 + (lane >> 4)) & 15);
    vsrc[i] = vt + (size_t)(h * 64 + dV) * 16384 + b * 4096 + gV * 8;
  }

  unsigned short* pw = &Psh[w][0];

  for (int kv0 = 0; kv0 < 4096; kv0 += 128) {
#pragma unroll
    for (int i = 0; i < 4; ++i)
      GLD_LDS16(ksrc + (size_t)(kv0 + i * 8) * 1024, Ksh + w * 2048 + i * 512);
#pragma unroll
    for (int i = 0; i < 4; ++i)
      GLD_LDS16(vsrc[i] + kv0, Vsh + w * 2048 + i * 512);
    __syncthreads();  // drains vmcnt before LDS reads

    // ---- S = Q K^T : 8 subtiles of 16 kv cols ----
    f32x4 S[8];
#pragma unroll
    for (int s = 0; s < 8; ++s) S[s] = zero4;
#pragma unroll
    for (int s = 0; s < 8; ++s) {
#pragma unroll
      for (int kk = 0; kk < 2; ++kk) {
        // row = s*16+fr, granule kk*4+fg, swz XOR (row&7)==(fr&7)
        bf16x8 kf = *(const bf16x8*)(Ksh + (s * 16 + fr) * 64 +
                                     (((kk * 4 + fg) ^ (fr & 7)) * 8));
        S[s] = __builtin_amdgcn_mfma_f32_16x16x32_bf16(kk ? qf1 : qf0, kf, S[s],
                                                       0, 0, 0);
      }
    }

    // ---- online softmax: local tree over 8 frags first, then 1 shuffle pass
    float cm[4];
#pragma unroll
    for (int j = 0; j < 4; ++j) cm[j] = -1e30f;
#pragma unroll
    for (int s = 0; s < 8; ++s)
#pragma unroll
      for (int j = 0; j < 4; ++j) {
        S[s][j] *= SC;
        cm[j] = fmaxf(cm[j], S[s][j]);
      }
#pragma unroll
    for (int mask = 1; mask <= 8; mask <<= 1)
#pragma unroll
      for (int j = 0; j < 4; ++j) cm[j] = fmaxf(cm[j], __shfl_xor(cm[j], mask));

    float fsc[4];
#pragma unroll
    for (int j = 0; j < 4; ++j) {
      float mn = fmaxf(m[j], cm[j]);
      fsc[j] = exp2f(m[j] - mn);
      m[j] = mn;
    }

    float rs[4] = {0.f, 0.f, 0.f, 0.f};
#pragma unroll
    for (int s = 0; s < 8; ++s)
#pragma unroll
      for (int j = 0; j < 4; ++j) {
        float p = exp2f(S[s][j] - m[j]);
        rs[j] += p;
        pw[(fg * 4 + j) * 136 + s * 16 + fr] = f2bf(p);
      }
#pragma unroll
    for (int mask = 1; mask <= 8; mask <<= 1)
#pragma unroll
      for (int j = 0; j < 4; ++j) rs[j] += __shfl_xor(rs[j], mask);
#pragma unroll
    for (int j = 0; j < 4; ++j) ssum[j] = ssum[j] * fsc[j] + rs[j];
#pragma unroll
    for (int n = 0; n < 4; ++n)
#pragma unroll
      for (int j = 0; j < 4; ++j) o[n][j] *= fsc[j];

    // ---- O += P V : 4 kk slices x 4 output subtiles ----
#pragma unroll
    for (int kk = 0; kk < 4; ++kk) {
      bf16x8 pa = *(const bf16x8*)(pw + fr * 136 + (kk * 4 + fg) * 8);
#pragma unroll
      for (int n = 0; n < 4; ++n) {
        // d = n*16+fr, granule kk*4+fg, swz XOR (d&15)==fr
        bf16x8 vf = *(const bf16x8*)(Vsh + (n * 16 + fr) * 128 +
                                     (((kk * 4 + fg) ^ fr) * 8));
        o[n] = __builtin_amdgcn_mfma_f32_16x16x32_bf16(pa, vf, o[n], 0, 0, 0);
      }
    }
    __syncthreads();  // protect Ksh/Vsh before next stage
  }

  // ---- normalize + store bf16 ----
#pragma unroll
  for (int j = 0; j < 4; ++j) {
    float inv = 1.0f / ssum[j];
    int row = b * 1024 + qt * 64 + w * 16 + fg * 4 + j;
#pragma unroll
    for (int n = 0; n < 4; ++n)
      ao[(size_t)row * 1024 + h * 64 + n * 16 + fr] = f2bf(o[n][j] * inv);
  }
}

// ---------------------------------------------------------------------------
// Launcher. Inputs: query(4M f32), kv_source(16M f32), w_q,w_k,w_v,w_o (1M f32).
// Workspace layout (128 MiB):
//   [0,8)    q_bf     [8,40)  kv_bf    [40,48) weights bf16 x4
//   [48,56)  qproj    [56,88) kproj    [88,120) v^T proj   [120,128) attn out
// ---------------------------------------------------------------------------
extern "C" void kernel_launch(void* const* d_in, const int* in_sizes, int n_in,
                              void* d_out, int out_size, void* d_ws, size_t ws_size,
                              hipStream_t stream) {
  const float* query = (const float*)d_in[0];
  const float* kvs = (const float*)d_in[1];
  const float* wq = (const float*)d_in[2];
  const float* wk = (const float*)d_in[3];
  const float* wv = (const float*)d_in[4];
  const float* wo = (const float*)d_in[5];
  float* out = (float*)d_out;
  char* ws = (char*)d_ws;
  const size_t MB = 1ull << 20;

  unsigned short* q_bf = (unsigned short*)(ws + 0 * MB);
  unsigned short* kv_bf = (unsigned short*)(ws + 8 * MB);
  unsigned short* wq_bf = (unsigned short*)(ws + 40 * MB);
  unsigned short* wk_bf = (unsigned short*)(ws + 42 * MB);
  unsigned short* wv_bf = (unsigned short*)(ws + 44 * MB);
  unsigned short* wo_bf = (unsigned short*)(ws + 46 * MB);
  unsigned short* qp = (unsigned short*)(ws + 48 * MB);
  unsigned short* kp = (unsigned short*)(ws + 56 * MB);
  unsigned short* vt = (unsigned short*)(ws + 88 * MB);
  unsigned short* ao = (unsigned short*)(ws + 120 * MB);

  cvt_f32_bf16<<<1024, 256, 0, stream>>>(query, q_bf, 4096 * 1024);
  cvt_f32_bf16<<<2048, 256, 0, stream>>>(kvs, kv_bf, 16384 * 1024);
  cvt_f32_bf16<<<256, 256, 0, stream>>>(wq, wq_bf, 1024 * 1024);
  cvt_f32_bf16<<<256, 256, 0, stream>>>(wk, wk_bf, 1024 * 1024);
  cvt_f32_bf16<<<256, 256, 0, stream>>>(wv, wv_bf, 1024 * 1024);
  cvt_f32_bf16<<<256, 256, 0, stream>>>(wo, wo_bf, 1024 * 1024);

  // q = query @ Wq^T            (4096 x 1024)
  gemm_bt<1><<<256, 256, 0, stream>>>(q_bf, wq_bf, qp, 4096, 1024, 1024, 1024);
  // k = kv @ Wk^T               (16384 x 1024)
  gemm_bt<1><<<1024, 256, 0, stream>>>(kv_bf, wk_bf, kp, 16384, 1024, 1024, 1024);
  // v^T = Wv @ kv^T             (1024 x 16384)  -- same kernel, swapped operands
  gemm_bt<1><<<1024, 256, 0, stream>>>(wv_bf, kv_bf, vt, 1024, 16384, 1024, 16384);

  attn_fwd<<<1024, 256, 0, stream>>>(qp, kp, vt, ao);

  // out = attn_out @ Wo^T       (4096 x 1024) f32
  gemm_bt<0><<<256, 256, 0, stream>>>(ao, wo_bf, out, 4096, 1024, 1024, 1024);
}

// Round 3
// 440.647 us; speedup vs baseline: 1.4649x; 1.2004x over previous
//
#include <hip/hip_runtime.h>
#include <hip/hip_bf16.h>

// ---------------------------------------------------------------------------
// FusionCrossAttention: out = softmax((x Wq^T)(kv Wk^T)^T / sqrt(hd)) (kv Wv^T) Wo^T
// B=4, T_q=1024, T_kv=4096, D=1024, H=16, hd=64
// Intermediates bf16, accumulation f32 via MFMA. Softmax scale (and log2e)
// folded into the W_q bf16 conversion.
// ---------------------------------------------------------------------------

typedef __attribute__((ext_vector_type(4))) float f32x4;
typedef __attribute__((ext_vector_type(8))) short bf16x8;

__device__ __forceinline__ unsigned short f2bf(float f) {
  unsigned u = __float_as_uint(f);
  u = (u + 0x7fffu + ((u >> 16) & 1u)) >> 16;   // round-to-nearest-even
  return (unsigned short)u;
}

#define GLD_LDS16(g, l)                                                     \
  __builtin_amdgcn_global_load_lds(                                        \
      (const __attribute__((address_space(1))) unsigned int*)(const void*)(g), \
      (__attribute__((address_space(3))) unsigned int*)(void*)(l), 16, 0, 0)

// ---------------------------------------------------------------------------
// Fused f32 -> bf16 conversion for all six inputs (one launch instead of six).
// W_q additionally scaled by 1/sqrt(64) * log2(e) BEFORE rounding (free).
// Segment sizes are multiples of 4 so float4 quads never straddle.
// ---------------------------------------------------------------------------
__global__ void cvt_all(const float* __restrict__ q, const float* __restrict__ kv,
                        const float* __restrict__ wq, const float* __restrict__ wk,
                        const float* __restrict__ wv, const float* __restrict__ wo,
                        unsigned short* __restrict__ q_bf,
                        unsigned short* __restrict__ kv_bf,
                        unsigned short* __restrict__ wq_bf,
                        unsigned short* __restrict__ wk_bf,
                        unsigned short* __restrict__ wv_bf,
                        unsigned short* __restrict__ wo_bf) {
  const int QN = 4194304, KVN = 16777216, WN = 1048576;
  const float SC = 0.125f * 1.44269504088896f;
  int total_quads = (QN + KVN + 4 * WN) >> 2;
  int stride = gridDim.x * blockDim.x;
  for (int t = blockIdx.x * blockDim.x + threadIdx.x; t < total_quads; t += stride) {
    int i = t << 2;
    const float* src;
    unsigned short* dst;
    float sc = 1.0f;
    int off;
    if (i < QN) { src = q; dst = q_bf; off = i; }
    else if (i < QN + KVN) { src = kv; dst = kv_bf; off = i - QN; }
    else if (i < QN + KVN + WN) { src = wq; dst = wq_bf; off = i - QN - KVN; sc = SC; }
    else if (i < QN + KVN + 2 * WN) { src = wk; dst = wk_bf; off = i - QN - KVN - WN; }
    else if (i < QN + KVN + 3 * WN) { src = wv; dst = wv_bf; off = i - QN - KVN - 2 * WN; }
    else { src = wo; dst = wo_bf; off = i - QN - KVN - 3 * WN; }
    float4 v = *(const float4*)(src + off);
    ushort4 r;
    r.x = f2bf(v.x * sc); r.y = f2bf(v.y * sc);
    r.z = f2bf(v.z * sc); r.w = f2bf(v.w * sc);
    *(ushort4*)(dst + off) = r;
  }
}

// ---------------------------------------------------------------------------
// 128x128x(K) GEMM, C[i][j] = sum_k A[i][k] * Bt[j][k]   (B^T input layout)
// m97 structure: BK=32, 4 waves (2x2), each wave 4x4 frags of 16x16x32 bf16.
// Requires M%128==0, N%128==0, K%32==0, grid = (M/128)*(N/128) % 8 == 0.
// ---------------------------------------------------------------------------
template <int WRITE_BF16>
__global__ __launch_bounds__(256) void gemm_bt(
    const unsigned short* __restrict__ A, const unsigned short* __restrict__ Bt,
    void* __restrict__ Cp, int M, int N, int K, int ldc) {
  __shared__ __align__(16) unsigned short Ash[4096];  // [128][32]
  __shared__ __align__(16) unsigned short Bsh[4096];  // [128][32]

  int tiles_n = N >> 7;
  int nwg = gridDim.x;
  int wg = blockIdx.x;
  int cpx = nwg >> 3;                       // bijective: nwg % 8 == 0 guaranteed
  wg = (wg & 7) * cpx + (wg >> 3);          // XCD-aware swizzle
  int tm = wg / tiles_n, tn = wg - tm * tiles_n;

  int tid = threadIdx.x;
  int lane = tid & 63, wave = tid >> 6;
  int wr = wave >> 1, wc = wave & 1;
  int brow = tm << 7, bcol = tn << 7;

  int fr = lane & 15, fg = lane >> 4;
  int swz = (fr >> 1) & 3;                  // read-side XOR mask

  int srow = lane >> 2;                     // 0..15 row within chunk
  int sg = (lane & 3) ^ ((srow >> 1) & 3);  // pre-swizzled source granule

  const unsigned short* aG0 = A + (size_t)(brow + wave * 32 + srow) * K + sg * 8;
  const unsigned short* aG1 = A + (size_t)(brow + wave * 32 + 16 + srow) * K + sg * 8;
  const unsigned short* bG0 = Bt + (size_t)(bcol + wave * 32 + srow) * K + sg * 8;
  const unsigned short* bG1 = Bt + (size_t)(bcol + wave * 32 + 16 + srow) * K + sg * 8;
  unsigned short* aL0 = Ash + wave * 1024;
  unsigned short* aL1 = Ash + wave * 1024 + 512;
  unsigned short* bL0 = Bsh + wave * 1024;
  unsigned short* bL1 = Bsh + wave * 1024 + 512;

  const f32x4 zero4 = {0.f, 0.f, 0.f, 0.f};
  f32x4 acc[4][4];
#pragma unroll
  for (int m = 0; m < 4; ++m)
#pragma unroll
    for (int n = 0; n < 4; ++n) acc[m][n] = zero4;

  for (int k0 = 0; k0 < K; k0 += 32) {
    GLD_LDS16(aG0 + k0, aL0);
    GLD_LDS16(aG1 + k0, aL1);
    GLD_LDS16(bG0 + k0, bL0);
    GLD_LDS16(bG1 + k0, bL1);
    __syncthreads();  // drains vmcnt before LDS reads

    bf16x8 af[4], bfr[4];
#pragma unroll
    for (int m = 0; m < 4; ++m) {
      int r = wr * 64 + m * 16 + fr;
      af[m] = *(const bf16x8*)(Ash + r * 32 + ((fg ^ swz) * 8));
    }
#pragma unroll
    for (int n = 0; n < 4; ++n) {
      int r = wc * 64 + n * 16 + fr;
      bfr[n] = *(const bf16x8*)(Bsh + r * 32 + ((fg ^ swz) * 8));
    }
#pragma unroll
    for (int m = 0; m < 4; ++m)
#pragma unroll
      for (int n = 0; n < 4; ++n)
        acc[m][n] =
            __builtin_amdgcn_mfma_f32_16x16x32_bf16(af[m], bfr[n], acc[m][n], 0, 0, 0);
    __syncthreads();  // all waves done reading before next stage overwrites
  }

  int crow = brow + wr * 64 + fg * 4;
  int ccol = bcol + wc * 64 + fr;
#pragma unroll
  for (int m = 0; m < 4; ++m)
#pragma unroll
    for (int n = 0; n < 4; ++n)
#pragma unroll
      for (int j = 0; j < 4; ++j) {
        size_t off = (size_t)(crow + m * 16 + j) * ldc + (ccol + n * 16);
        if (WRITE_BF16)
          ((unsigned short*)Cp)[off] = f2bf(acc[m][n][j]);
        else
          ((float*)Cp)[off] = acc[m][n][j];
      }
}

// ---------------------------------------------------------------------------
// Flash attention v3. Grid: 512 blocks = (b:4, h:16, qtile:8 of 128 rows),
// XCD-swizzled (64 consecutive logical blocks per XCD = 8 whole (b,h) groups).
// Block: 512 threads / 8 waves; each wave owns 16 q-rows; KVBLK=128.
// K staged [128][64] (granule swz g^(r&7)); V from transposed projection vt
// as [64][128] (swz g^(d&15)). P processed in two 64-col halves through a
// per-wave [16][72] LDS buffer (stride 144B). Row-sum of P computed by an
// extra MFMA against an all-ones B fragment (no shuffle reduce). Rescale of
// o/ssum skipped exactly when the running max did not grow.
// LDS: 16K + 16K + 8*2304 = 51.2 KB -> 3 blocks/CU.
// ---------------------------------------------------------------------------
__global__ __launch_bounds__(512) void attn_fwd(
    const unsigned short* __restrict__ qp,  // (4096, 1024), pre-scaled by SC
    const unsigned short* __restrict__ kp,  // (16384, 1024)
    const unsigned short* __restrict__ vt,  // (1024, 16384) = V^T per (b,h)
    unsigned short* __restrict__ ao) {      // (4096, 1024)
  __shared__ __align__(16) unsigned short Ksh[128 * 64];    // 16 KB
  __shared__ __align__(16) unsigned short Vsh[64 * 128];    // 16 KB
  __shared__ __align__(16) unsigned short Psh[8][16 * 72];  // 18 KB

  int idx = (blockIdx.x & 7) * 64 + (blockIdx.x >> 3);
  int qt = idx & 7;
  int h = (idx >> 3) & 15;
  int b = idx >> 7;
  int tid = threadIdx.x;
  int lane = tid & 63, w = tid >> 6;
  int fr = lane & 15, fg = lane >> 4;

  // Q fragments (A-operand layout); SC already folded into W_q.
  int qrow = b * 1024 + qt * 128 + w * 16 + fr;
  bf16x8 qf0 = *(const bf16x8*)(qp + (size_t)qrow * 1024 + h * 64 + fg * 8);
  bf16x8 qf1 = *(const bf16x8*)(qp + (size_t)qrow * 1024 + h * 64 + 32 + fg * 8);

  bf16x8 ones;
#pragma unroll
  for (int e = 0; e < 8; ++e) ones[e] = (short)0x3F80;  // 1.0 bf16

  const f32x4 zero4 = {0.f, 0.f, 0.f, 0.f};
  f32x4 o[4];
#pragma unroll
  for (int n = 0; n < 4; ++n) o[n] = zero4;
  float m[4], ssum[4];
#pragma unroll
  for (int j = 0; j < 4; ++j) { m[j] = -1e30f; ssum[j] = 0.f; }

  // K staging: wave w stages rows w*16..w*16+15 (2 calls x 8 rows x 8 granules)
  int rK = w * 16 + (lane >> 3);
  int gK = (lane & 7) ^ ((lane >> 3) & 7);
  const unsigned short* ksrc = kp + (size_t)(b * 4096 + rK) * 1024 + h * 64 + gK * 8;
  // V staging: wave w stages d-rows w*8..w*8+7 (2 calls x 4 rows x 16 granules)
  int dV = w * 8 + (lane >> 4);
  int gV = (lane & 15) ^ (dV & 15);
  int gV1 = (lane & 15) ^ ((dV + 4) & 15);
  const unsigned short* vsrc0 = vt + (size_t)(h * 64 + dV) * 16384 + b * 4096 + gV * 8;
  const unsigned short* vsrc1 =
      vt + (size_t)(h * 64 + dV + 4) * 16384 + b * 4096 + gV1 * 8;

  unsigned short* pw = &Psh[w][0];

  for (int kv0 = 0; kv0 < 4096; kv0 += 128) {
    GLD_LDS16(ksrc + (size_t)kv0 * 1024, Ksh + w * 1024);
    GLD_LDS16(ksrc + (size_t)kv0 * 1024 + 8192, Ksh + w * 1024 + 512);
    GLD_LDS16(vsrc0 + kv0, Vsh + w * 1024);
    GLD_LDS16(vsrc1 + kv0, Vsh + w * 1024 + 512);
    __syncthreads();  // drains vmcnt before LDS reads

    // ---- S = Q K^T : 8 subtiles of 16 kv cols (scores pre-scaled) ----
    f32x4 S[8];
#pragma unroll
    for (int s = 0; s < 8; ++s) S[s] = zero4;
    __builtin_amdgcn_s_setprio(1);
#pragma unroll
    for (int s = 0; s < 8; ++s) {
      const unsigned short* krow = Ksh + (s * 16 + fr) * 64;
      bf16x8 kf0 = *(const bf16x8*)(krow + ((fg ^ (fr & 7)) * 8));
      bf16x8 kf1 = *(const bf16x8*)(krow + (((4 + fg) ^ (fr & 7)) * 8));
      S[s] = __builtin_amdgcn_mfma_f32_16x16x32_bf16(qf0, kf0, S[s], 0, 0, 0);
      S[s] = __builtin_amdgcn_mfma_f32_16x16x32_bf16(qf1, kf1, S[s], 0, 0, 0);
    }
    __builtin_amdgcn_s_setprio(0);

    // ---- row max: local tree over 8 frags, then 4-mask shuffle ----
    float cm[4];
#pragma unroll
    for (int j = 0; j < 4; ++j) cm[j] = S[0][j];
#pragma unroll
    for (int s = 1; s < 8; ++s)
#pragma unroll
      for (int j = 0; j < 4; ++j) cm[j] = fmaxf(cm[j], S[s][j]);
#pragma unroll
    for (int mask = 1; mask <= 8; mask <<= 1)
#pragma unroll
      for (int j = 0; j < 4; ++j) cm[j] = fmaxf(cm[j], __shfl_xor(cm[j], mask));

    // ---- rescale only if the running max grew (skip is EXACT: fsc==1) ----
    bool grow = (cm[0] > m[0]) | (cm[1] > m[1]) | (cm[2] > m[2]) | (cm[3] > m[3]);
    if (__any(grow)) {
#pragma unroll
      for (int j = 0; j < 4; ++j) {
        float mn = fmaxf(m[j], cm[j]);
        float fsc = exp2f(m[j] - mn);
        m[j] = mn;
        ssum[j] *= fsc;
#pragma unroll
        for (int n = 0; n < 4; ++n) o[n][j] *= fsc;
      }
    }

    // ---- two 64-col halves: P -> LDS, then PV + MFMA row-sum ----
    f32x4 rsum = zero4;
#pragma unroll
    for (int hf = 0; hf < 2; ++hf) {
#pragma unroll
      for (int sp = 0; sp < 4; sp += 2) {
        int s = hf * 4 + sp;
#pragma unroll
        for (int j = 0; j < 4; ++j) {
          float p0 = exp2f(S[s][j] - m[j]);
          float p1 = exp2f(S[s + 1][j] - m[j]);
          __hip_bfloat162 pk = __float22bfloat162_rn(float2{p0, p1});
          unsigned u = *reinterpret_cast<unsigned*>(&pk);
          int base = (fg * 4 + j) * 72 + sp * 16 + fr;
          pw[base] = (unsigned short)u;
          pw[base + 16] = (unsigned short)(u >> 16);
        }
      }
      __builtin_amdgcn_s_setprio(1);
#pragma unroll
      for (int kk = 0; kk < 2; ++kk) {
        bf16x8 pa = *(const bf16x8*)(pw + fr * 72 + (kk * 4 + fg) * 8);
        rsum = __builtin_amdgcn_mfma_f32_16x16x32_bf16(pa, ones, rsum, 0, 0, 0);
        int g = hf * 8 + kk * 4 + fg;
#pragma unroll
        for (int n = 0; n < 4; ++n) {
          bf16x8 vf = *(const bf16x8*)(Vsh + (n * 16 + fr) * 128 + ((g ^ fr) * 8));
          o[n] = __builtin_amdgcn_mfma_f32_16x16x32_bf16(pa, vf, o[n], 0, 0, 0);
        }
      }
      __builtin_amdgcn_s_setprio(0);
    }
#pragma unroll
    for (int j = 0; j < 4; ++j) ssum[j] += rsum[j];
    __syncthreads();  // protect Ksh/Vsh before next stage
  }

  // ---- normalize + store bf16 ----
#pragma unroll
  for (int j = 0; j < 4; ++j) {
    float inv = 1.0f / ssum[j];
    int row = b * 1024 + qt * 128 + w * 16 + fg * 4 + j;
#pragma unroll
    for (int n = 0; n < 4; ++n)
      ao[(size_t)row * 1024 + h * 64 + n * 16 + fr] = f2bf(o[n][j] * inv);
  }
}

// ---------------------------------------------------------------------------
// Launcher. Inputs: query(4M f32), kv_source(16M f32), w_q,w_k,w_v,w_o (1M f32).
// Workspace layout (128 MiB):
//   [0,8)    q_bf     [8,40)  kv_bf    [40,48) weights bf16 x4
//   [48,56)  qproj    [56,88) kproj    [88,120) v^T proj   [120,128) attn out
// ---------------------------------------------------------------------------
extern "C" void kernel_launch(void* const* d_in, const int* in_sizes, int n_in,
                              void* d_out, int out_size, void* d_ws, size_t ws_size,
                              hipStream_t stream) {
  const float* query = (const float*)d_in[0];
  const float* kvs = (const float*)d_in[1];
  const float* wq = (const float*)d_in[2];
  const float* wk = (const float*)d_in[3];
  const float* wv = (const float*)d_in[4];
  const float* wo = (const float*)d_in[5];
  float* out = (float*)d_out;
  char* ws = (char*)d_ws;
  const size_t MB = 1ull << 20;

  unsigned short* q_bf = (unsigned short*)(ws + 0 * MB);
  unsigned short* kv_bf = (unsigned short*)(ws + 8 * MB);
  unsigned short* wq_bf = (unsigned short*)(ws + 40 * MB);
  unsigned short* wk_bf = (unsigned short*)(ws + 42 * MB);
  unsigned short* wv_bf = (unsigned short*)(ws + 44 * MB);
  unsigned short* wo_bf = (unsigned short*)(ws + 46 * MB);
  unsigned short* qp = (unsigned short*)(ws + 48 * MB);
  unsigned short* kp = (unsigned short*)(ws + 56 * MB);
  unsigned short* vt = (unsigned short*)(ws + 88 * MB);
  unsigned short* ao = (unsigned short*)(ws + 120 * MB);

  cvt_all<<<2048, 256, 0, stream>>>(query, kvs, wq, wk, wv, wo, q_bf, kv_bf,
                                    wq_bf, wk_bf, wv_bf, wo_bf);

  // q = query @ (Wq*SC)^T       (4096 x 1024)
  gemm_bt<1><<<256, 256, 0, stream>>>(q_bf, wq_bf, qp, 4096, 1024, 1024, 1024);
  // k = kv @ Wk^T               (16384 x 1024)
  gemm_bt<1><<<1024, 256, 0, stream>>>(kv_bf, wk_bf, kp, 16384, 1024, 1024, 1024);
  // v^T = Wv @ kv^T             (1024 x 16384)  -- same kernel, swapped operands
  gemm_bt<1><<<1024, 256, 0, stream>>>(wv_bf, kv_bf, vt, 1024, 16384, 1024, 16384);

  attn_fwd<<<512, 512, 0, stream>>>(qp, kp, vt, ao);

  // out = attn_out @ Wo^T       (4096 x 1024) f32
  gemm_bt<0><<<256, 256, 0, stream>>>(ao, wo_bf, out, 4096, 1024, 1024, 1024);
}